// Round 1
// baseline (496.450 us; speedup 1.0000x reference)
//
#include <hip/hip_runtime.h>
#include <hip/hip_bf16.h>
#include <stdint.h>

typedef unsigned int u32;
typedef unsigned long long u64;
typedef __attribute__((ext_vector_type(8))) short bf16x8;
typedef __attribute__((ext_vector_type(4))) float f32x4;

#define NROWS 8192    // 16*512
#define NCODES 4096
#define DIM 4096
#define KSTEPS (DIM / 32)

// ---------------- workspace layout (bytes) ----------------
// A_bf16   : [NROWS][DIM]  ushort   = 67108864
// B_bf16   : [NCODES][DIM] ushort   = 33554432
// norms    : [NCODES] float         = 16384
// argmin   : [NROWS] u64            = 65536
// counts   : [NCODES] u32           = 16384
// sse      : float
#define OFF_A      0
#define OFF_B      67108864UL
#define OFF_NORMS  100663296UL
#define OFF_AMIN   100679680UL
#define OFF_COUNTS 100745216UL
#define OFF_SSE    100761600UL

__device__ __forceinline__ void stage16(const void* g, void* l) {
  __builtin_amdgcn_global_load_lds(
      (const __attribute__((address_space(1))) u32*)g,
      (__attribute__((address_space(3))) u32*)l, 16, 0, 0);
}

__device__ __forceinline__ ushort f2bf(float f) {
  u32 b = __float_as_uint(f);
  b += 0x7FFFu + ((b >> 16) & 1u);   // RNE (inputs are finite, no NaN care)
  return (ushort)(b >> 16);
}

__device__ __forceinline__ float waveRed(float s) {
#pragma unroll
  for (int off = 32; off > 0; off >>= 1) s += __shfl_down(s, off);
  return s;
}

// ---------------- init ----------------
__global__ void k_init(u64* __restrict__ amin, u32* __restrict__ counts,
                       float* __restrict__ sse) {
  int t = blockIdx.x * 256 + threadIdx.x;
  if (t < NROWS) amin[t] = ~0ULL;
  if (t < NCODES) counts[t] = 0u;
  if (t == 0) *sse = 0.0f;
}

// ---------------- fp32 -> bf16 (inputs) ----------------
__global__ void k_cvtA(const float4* __restrict__ in, ushort4* __restrict__ outA,
                       int n4) {
  int i = blockIdx.x * blockDim.x + threadIdx.x;
  int stride = gridDim.x * blockDim.x;
  for (; i < n4; i += stride) {
    float4 v = in[i];
    ushort4 o;
    o.x = f2bf(v.x); o.y = f2bf(v.y); o.z = f2bf(v.z); o.w = f2bf(v.w);
    outA[i] = o;
  }
}

// ---------------- fp32 -> bf16 (codebook) + ||e||^2 ----------------
__global__ void k_cvtB(const float* __restrict__ cb, ushort* __restrict__ Bb,
                       float* __restrict__ norms) {
  int row = blockIdx.x;
  const float4* src = (const float4*)(cb + (size_t)row * DIM);
  ushort4* dst = (ushort4*)(Bb + (size_t)row * DIM);
  float s = 0.0f;
  for (int j = threadIdx.x; j < DIM / 4; j += 256) {
    float4 v = src[j];
    s += v.x * v.x + v.y * v.y + v.z * v.z + v.w * v.w;
    ushort4 o;
    o.x = f2bf(v.x); o.y = f2bf(v.y); o.z = f2bf(v.z); o.w = f2bf(v.w);
    dst[j] = o;
  }
  s = waveRed(s);
  __shared__ float red[4];
  int wid = threadIdx.x >> 6, lane = threadIdx.x & 63;
  if (lane == 0) red[wid] = s;
  __syncthreads();
  if (threadIdx.x == 0) norms[row] = red[0] + red[1] + red[2] + red[3];
}

// ---------------- GEMM (x . e^T) + per-row argmin of ||e||^2 - 2 x.e ----------
// 128x128 tile, BK=32, 4 waves (2x2 of 64x64), 16x16x32 bf16 MFMA.
__launch_bounds__(256)
__global__ void k_gemm_argmin(const ushort* __restrict__ A,
                              const ushort* __restrict__ B,
                              const float* __restrict__ norms,
                              u64* __restrict__ amin) {
  __shared__ ushort As[128 * 32];
  __shared__ ushort Bs[128 * 32];

  const int bm = blockIdx.x;           // M tile (64)
  const int bn = blockIdx.y;           // N tile (32)
  const int tid = threadIdx.x;
  const int w = tid >> 6;
  const int lane = tid & 63;
  const int wr = w >> 1, wc = w & 1;   // wave 2x2 grid
  const int g = lane >> 4, c = lane & 15;

  const char* Ab = (const char*)A;
  const char* Bb = (const char*)B;
  const size_t rowA0 = (size_t)bm * 128;
  const size_t rowB0 = (size_t)bn * 128;

  f32x4 acc[4][4] = {};

  for (int kt = 0; kt < KSTEPS; ++kt) {
    __syncthreads();
    // stage A and B tiles (128 rows x 32 k, 64 B/row) via global_load_lds
#pragma unroll
    for (int j = 0; j < 2; ++j) {
      int o = j * 4096 + tid * 16;
      int row = o >> 6, colb = o & 63;
      stage16(Ab + (rowA0 + row) * (DIM * 2) + (size_t)kt * 64 + colb,
              (char*)As + o);
      stage16(Bb + (rowB0 + row) * (DIM * 2) + (size_t)kt * 64 + colb,
              (char*)Bs + o);
    }
    __syncthreads();

    bf16x8 af[4], bf[4];
#pragma unroll
    for (int m = 0; m < 4; ++m)
      af[m] = *(const bf16x8*)&As[(wr * 64 + m * 16 + c) * 32 + g * 8];
#pragma unroll
    for (int n = 0; n < 4; ++n)
      bf[n] = *(const bf16x8*)&Bs[(wc * 64 + n * 16 + c) * 32 + g * 8];
#pragma unroll
    for (int m = 0; m < 4; ++m)
#pragma unroll
      for (int n = 0; n < 4; ++n)
        acc[m][n] = __builtin_amdgcn_mfma_f32_16x16x32_bf16(af[m], bf[n],
                                                            acc[m][n], 0, 0, 0);
  }

  // epilogue: d = ||e||^2 - 2 x.e ; argmin over this block's 128 cols
  const int rowBase = bm * 128 + wr * 64;
  const int colBase = bn * 128 + wc * 64;
  float nr[4];
#pragma unroll
  for (int n = 0; n < 4; ++n) nr[n] = norms[colBase + n * 16 + c];

#pragma unroll
  for (int m = 0; m < 4; ++m) {
#pragma unroll
    for (int j = 0; j < 4; ++j) {
      u64 key = ~0ULL;
#pragma unroll
      for (int n = 0; n < 4; ++n) {
        float d = nr[n] - 2.0f * acc[m][n][j];
        u32 u = __float_as_uint(d);
        u = (u & 0x80000000u) ? ~u : (u | 0x80000000u);
        u64 k2 = ((u64)u << 32) | (u32)(colBase + n * 16 + c);
        if (k2 < key) key = k2;
      }
#pragma unroll
      for (int off = 1; off < 16; off <<= 1) {
        u64 o = __shfl_xor(key, off);
        if (o < key) key = o;
      }
      if (c == 0) atomicMin(&amin[rowBase + m * 16 + g * 4 + j], key);
    }
  }
}

// ---------------- gather + output write + SSE + counts ----------------
__global__ void k_out(const float4* __restrict__ in, const float4* __restrict__ cb,
                      const u64* __restrict__ amin, float4* __restrict__ out,
                      u32* __restrict__ counts, float* __restrict__ sse) {
  int r = blockIdx.x;
  u32 idx = (u32)(amin[r] & 0xFFFFFFFFu);
  if (threadIdx.x == 0) atomicAdd(&counts[idx], 1u);
  const float4* crow = cb + (size_t)idx * (DIM / 4);
  const float4* xrow = in + (size_t)r * (DIM / 4);
  float4* orow = out + (size_t)r * (DIM / 4);
  float s = 0.0f;
  for (int j = threadIdx.x; j < DIM / 4; j += 256) {
    float4 q = crow[j];
    float4 x = xrow[j];
    orow[j] = q;  // quantized_st == quantized in value
    float dx = q.x - x.x, dy = q.y - x.y, dz = q.z - x.z, dw = q.w - x.w;
    s += dx * dx + dy * dy + dz * dz + dw * dw;
  }
  s = waveRed(s);
  __shared__ float red[4];
  int wid = threadIdx.x >> 6, lane = threadIdx.x & 63;
  if (lane == 0) red[wid] = s;
  __syncthreads();
  if (threadIdx.x == 0) atomicAdd(sse, red[0] + red[1] + red[2] + red[3]);
}

// ---------------- finalize: loss + perplexity ----------------
__global__ void k_final(const u32* __restrict__ counts, const float* __restrict__ sse,
                        float* __restrict__ out) {
  float ent = 0.0f;
  for (int i = threadIdx.x; i < NCODES; i += 256) {
    float p = (float)counts[i] * (1.0f / (float)NROWS);
    ent -= p * logf(p + 1e-10f);
  }
  ent = waveRed(ent);
  __shared__ float red[4];
  int wid = threadIdx.x >> 6, lane = threadIdx.x & 63;
  if (lane == 0) red[wid] = ent;
  __syncthreads();
  if (threadIdx.x == 0) {
    float e = red[0] + red[1] + red[2] + red[3];
    out[(size_t)NROWS * DIM] = 1.25f * (*sse) * (1.0f / (float)((size_t)NROWS * DIM));
    out[(size_t)NROWS * DIM + 1] = expf(e);
  }
}

extern "C" void kernel_launch(void* const* d_in, const int* in_sizes, int n_in,
                              void* d_out, int out_size, void* d_ws, size_t ws_size,
                              hipStream_t stream) {
  const float* d_inputs = (const float*)d_in[0];
  const float* d_cb = (const float*)d_in[1];
  float* out = (float*)d_out;
  char* ws = (char*)d_ws;

  ushort* A = (ushort*)(ws + OFF_A);
  ushort* B = (ushort*)(ws + OFF_B);
  float* norms = (float*)(ws + OFF_NORMS);
  u64* amin = (u64*)(ws + OFF_AMIN);
  u32* counts = (u32*)(ws + OFF_COUNTS);
  float* sse = (float*)(ws + OFF_SSE);

  k_init<<<32, 256, 0, stream>>>(amin, counts, sse);
  k_cvtA<<<2048, 256, 0, stream>>>((const float4*)d_inputs, (ushort4*)A,
                                   (int)((size_t)NROWS * DIM / 4));
  k_cvtB<<<NCODES, 256, 0, stream>>>(d_cb, B, norms);
  dim3 grid(NROWS / 128, NCODES / 128);
  k_gemm_argmin<<<grid, 256, 0, stream>>>(A, B, norms, amin);
  k_out<<<NROWS, 256, 0, stream>>>((const float4*)d_inputs, (const float4*)d_cb,
                                   amin, (float4*)out, counts, sse);
  k_final<<<1, 256, 0, stream>>>(counts, sse, out);
}

// Round 2
// 351.856 us; speedup vs baseline: 1.4109x; 1.4109x over previous
//
#include <hip/hip_runtime.h>
#include <hip/hip_bf16.h>
#include <stdint.h>

typedef unsigned int u32;
typedef unsigned char u8;
typedef unsigned long long u64;
typedef __attribute__((ext_vector_type(8))) int i32x8;
typedef __attribute__((ext_vector_type(4))) float f32x4;

#define NROWS 8192    // 16*512
#define NCODES 4096
#define DIM 4096
#define BK 128
#define KSTEPS (DIM / BK)   // 32

// ---------------- workspace layout (bytes) ----------------
// A_fp8   : [NROWS][DIM]  u8  = 33554432
// B_fp8   : [NCODES][DIM] u8  = 16777216   (codebook scaled by 4096)
// norms   : [NCODES] float (unscaled ||e||^2)
// argmin  : [NROWS] u64
// counts  : [NCODES] u32
// sse     : float
#define OFF_A      0UL
#define OFF_B      33554432UL
#define OFF_NORMS  50331648UL
#define OFF_AMIN   50348032UL
#define OFF_COUNTS 50413568UL
#define OFF_SSE    50429952UL

__device__ __forceinline__ void stage16(const void* g, void* l) {
  __builtin_amdgcn_global_load_lds(
      (const __attribute__((address_space(1))) u32*)g,
      (__attribute__((address_space(3))) u32*)l, 16, 0, 0);
}

// float -> OCP e4m3fn, RNE, saturate to 448. Data is finite (no NaN path).
__device__ __forceinline__ u32 f2fp8(float f) {
  u32 u = __float_as_uint(f);
  u32 sign = (u >> 24) & 0x80u;
  u32 mag = u & 0x7FFFFFFFu;
  if (mag > 0x43E00000u) mag = 0x43E00000u;          // sat to 448
  u32 b;
  if (mag < 0x3C800000u) {                            // < 2^-6 : subnormal
    b = (u32)__float2int_rn(__uint_as_float(mag) * 512.0f);
  } else {
    u32 m = mag + 0x7FFFFu + ((mag >> 20) & 1u);      // RNE at 20-bit boundary
    u32 e = (m >> 23) - 127u;
    b = (((e + 7u) << 3) | ((m >> 20) & 7u)) & 0x7Fu;
  }
  return sign | b;
}

__device__ __forceinline__ u32 pack4(float4 v) {
  return f2fp8(v.x) | (f2fp8(v.y) << 8) | (f2fp8(v.z) << 16) | (f2fp8(v.w) << 24);
}

__device__ __forceinline__ float waveRed(float s) {
#pragma unroll
  for (int off = 32; off > 0; off >>= 1) s += __shfl_down(s, off);
  return s;
}

// ---------------- init ----------------
__global__ void k_init(u64* __restrict__ amin, u32* __restrict__ counts,
                       float* __restrict__ sse) {
  int t = blockIdx.x * 256 + threadIdx.x;
  if (t < NROWS) amin[t] = ~0ULL;
  if (t < NCODES) counts[t] = 0u;
  if (t == 0) *sse = 0.0f;
}

// ---------------- fp32 -> fp8 (inputs), 16 elems/thread ----------------
__global__ void k_cvtA(const float4* __restrict__ in, uint4* __restrict__ outA,
                       int n16) {
  int i = blockIdx.x * blockDim.x + threadIdx.x;
  int stride = gridDim.x * blockDim.x;
  for (; i < n16; i += stride) {
    float4 v0 = in[i * 4 + 0], v1 = in[i * 4 + 1];
    float4 v2 = in[i * 4 + 2], v3 = in[i * 4 + 3];
    uint4 o;
    o.x = pack4(v0); o.y = pack4(v1); o.z = pack4(v2); o.w = pack4(v3);
    outA[i] = o;
  }
}

// ---------------- fp32 -> fp8 (codebook * 4096) + fp32 ||e||^2 ----------------
__global__ void k_cvtB(const float* __restrict__ cb, u32* __restrict__ Bb,
                       float* __restrict__ norms) {
  int row = blockIdx.x;
  const float4* src = (const float4*)(cb + (size_t)row * DIM);
  u32* dst = Bb + (size_t)row * (DIM / 4);
  float s = 0.0f;
  for (int j = threadIdx.x; j < DIM / 4; j += 256) {
    float4 v = src[j];
    s += v.x * v.x + v.y * v.y + v.z * v.z + v.w * v.w;
    float4 sv;
    sv.x = v.x * 4096.0f; sv.y = v.y * 4096.0f;
    sv.z = v.z * 4096.0f; sv.w = v.w * 4096.0f;
    dst[j] = pack4(sv);
  }
  s = waveRed(s);
  __shared__ float red[4];
  int wid = threadIdx.x >> 6, lane = threadIdx.x & 63;
  if (lane == 0) red[wid] = s;
  __syncthreads();
  if (threadIdx.x == 0) norms[row] = red[0] + red[1] + red[2] + red[3];
}

// ---------------- MX-fp8 GEMM (x . e^T) + per-row argmin ----------------
// 128x128 tile, BK=128 (fp8), 4 waves (2x2 of 64x64), 16x16x128 f8f6f4 MFMA
// with unit scales (0x7F = 1.0). acc = 4096 * (x.e); d = ||e||^2 - acc*2/4096.
__launch_bounds__(256)
__global__ void k_gemm_argmin(const u8* __restrict__ A,
                              const u8* __restrict__ B,
                              const float* __restrict__ norms,
                              u64* __restrict__ amin) {
  __shared__ u8 As[128 * BK];   // 16 KiB
  __shared__ u8 Bs[128 * BK];   // 16 KiB

  const int bm = blockIdx.x;
  const int bn = blockIdx.y;
  const int tid = threadIdx.x;
  const int w = tid >> 6;
  const int lane = tid & 63;
  const int wr = w >> 1, wc = w & 1;
  const int g = lane >> 4, c = lane & 15;

  const size_t rowA0 = (size_t)bm * 128;
  const size_t rowB0 = (size_t)bn * 128;

  f32x4 acc[4][4] = {};

  for (int kt = 0; kt < KSTEPS; ++kt) {
    __syncthreads();
    // stage A and B tiles: 128 rows x 128 B each, 4 rounds of 16 B/thread
#pragma unroll
    for (int j = 0; j < 4; ++j) {
      int o = j * 4096 + tid * 16;
      int row = o >> 7, colb = o & 127;
      stage16(A + (rowA0 + row) * DIM + (size_t)kt * BK + colb, (char*)As + o);
      stage16(B + (rowB0 + row) * DIM + (size_t)kt * BK + colb, (char*)Bs + o);
    }
    __syncthreads();

    i32x8 af[4], bv[4];
#pragma unroll
    for (int m = 0; m < 4; ++m)
      af[m] = *(const i32x8*)&As[(wr * 64 + m * 16 + c) * BK + g * 32];
#pragma unroll
    for (int n = 0; n < 4; ++n)
      bv[n] = *(const i32x8*)&Bs[(wc * 64 + n * 16 + c) * BK + g * 32];
#pragma unroll
    for (int m = 0; m < 4; ++m)
#pragma unroll
      for (int n = 0; n < 4; ++n)
        acc[m][n] = __builtin_amdgcn_mfma_scale_f32_16x16x128_f8f6f4(
            af[m], bv[n], acc[m][n], 0, 0, 0, 0x7F7F7F7F, 0, 0x7F7F7F7F);
  }

  // epilogue: d = ||e||^2 - (2/4096) * acc ; argmin over this block's 128 cols
  const int rowBase = bm * 128 + wr * 64;
  const int colBase = bn * 128 + wc * 64;
  float nr[4];
#pragma unroll
  for (int n = 0; n < 4; ++n) nr[n] = norms[colBase + n * 16 + c];

#pragma unroll
  for (int m = 0; m < 4; ++m) {
#pragma unroll
    for (int j = 0; j < 4; ++j) {
      u64 key = ~0ULL;
#pragma unroll
      for (int n = 0; n < 4; ++n) {
        float d = nr[n] - acc[m][n][j] * 4.8828125e-4f;   // 2/4096
        u32 u = __float_as_uint(d);
        u = (u & 0x80000000u) ? ~u : (u | 0x80000000u);
        u64 k2 = ((u64)u << 32) | (u32)(colBase + n * 16 + c);
        if (k2 < key) key = k2;
      }
#pragma unroll
      for (int off = 1; off < 16; off <<= 1) {
        u64 o = __shfl_xor(key, off);
        if (o < key) key = o;
      }
      if (c == 0) atomicMin(&amin[rowBase + m * 16 + g * 4 + j], key);
    }
  }
}

// ---------------- gather + output write + SSE + counts ----------------
__global__ void k_out(const float4* __restrict__ in, const float4* __restrict__ cb,
                      const u64* __restrict__ amin, float4* __restrict__ out,
                      u32* __restrict__ counts, float* __restrict__ sse) {
  int r = blockIdx.x;
  u32 idx = (u32)(amin[r] & 0xFFFFFFFFu);
  if (threadIdx.x == 0) atomicAdd(&counts[idx], 1u);
  const float4* crow = cb + (size_t)idx * (DIM / 4);
  const float4* xrow = in + (size_t)r * (DIM / 4);
  float4* orow = out + (size_t)r * (DIM / 4);
  float s = 0.0f;
  for (int j = threadIdx.x; j < DIM / 4; j += 256) {
    float4 q = crow[j];
    float4 x = xrow[j];
    orow[j] = q;  // quantized_st == quantized in value
    float dx = q.x - x.x, dy = q.y - x.y, dz = q.z - x.z, dw = q.w - x.w;
    s += dx * dx + dy * dy + dz * dz + dw * dw;
  }
  s = waveRed(s);
  __shared__ float red[4];
  int wid = threadIdx.x >> 6, lane = threadIdx.x & 63;
  if (lane == 0) red[wid] = s;
  __syncthreads();
  if (threadIdx.x == 0) atomicAdd(sse, red[0] + red[1] + red[2] + red[3]);
}

// ---------------- finalize: loss + perplexity ----------------
__global__ void k_final(const u32* __restrict__ counts, const float* __restrict__ sse,
                        float* __restrict__ out) {
  float ent = 0.0f;
  for (int i = threadIdx.x; i < NCODES; i += 256) {
    float p = (float)counts[i] * (1.0f / (float)NROWS);
    ent -= p * logf(p + 1e-10f);
  }
  ent = waveRed(ent);
  __shared__ float red[4];
  int wid = threadIdx.x >> 6, lane = threadIdx.x & 63;
  if (lane == 0) red[wid] = ent;
  __syncthreads();
  if (threadIdx.x == 0) {
    float e = red[0] + red[1] + red[2] + red[3];
    out[(size_t)NROWS * DIM] = 1.25f * (*sse) * (1.0f / (float)((size_t)NROWS * DIM));
    out[(size_t)NROWS * DIM + 1] = expf(e);
  }
}

extern "C" void kernel_launch(void* const* d_in, const int* in_sizes, int n_in,
                              void* d_out, int out_size, void* d_ws, size_t ws_size,
                              hipStream_t stream) {
  const float* d_inputs = (const float*)d_in[0];
  const float* d_cb = (const float*)d_in[1];
  float* out = (float*)d_out;
  char* ws = (char*)d_ws;

  u8* A = (u8*)(ws + OFF_A);
  u8* B = (u8*)(ws + OFF_B);
  float* norms = (float*)(ws + OFF_NORMS);
  u64* amin = (u64*)(ws + OFF_AMIN);
  u32* counts = (u32*)(ws + OFF_COUNTS);
  float* sse = (float*)(ws + OFF_SSE);

  k_init<<<32, 256, 0, stream>>>(amin, counts, sse);
  k_cvtA<<<2048, 256, 0, stream>>>((const float4*)d_inputs, (uint4*)A,
                                   (int)((size_t)NROWS * DIM / 16));
  k_cvtB<<<NCODES, 256, 0, stream>>>(d_cb, (u32*)B, norms);
  dim3 grid(NROWS / 128, NCODES / 128);
  k_gemm_argmin<<<grid, 256, 0, stream>>>(A, B, norms, amin);
  k_out<<<NROWS, 256, 0, stream>>>((const float4*)d_inputs, (const float4*)d_cb,
                                   amin, (float4*)out, counts, sse);
  k_final<<<1, 256, 0, stream>>>(counts, sse, out);
}

// Round 3
// 268.958 us; speedup vs baseline: 1.8458x; 1.3082x over previous
//
#include <hip/hip_runtime.h>
#include <hip/hip_bf16.h>
#include <stdint.h>

typedef unsigned int u32;
typedef unsigned char u8;
typedef unsigned long long u64;
typedef __attribute__((ext_vector_type(8))) int i32x8;
typedef __attribute__((ext_vector_type(4))) int i32x4;
typedef __attribute__((ext_vector_type(4))) float f32x4;

#define NROWS 8192    // 16*512
#define NCODES 4096
#define DIM 4096
#define BK 128
#define KSTEPS (DIM / BK)   // 32

// ---------------- workspace layout (bytes) ----------------
// A_fp8   : [NROWS][DIM]  u8  = 33554432
// B_fp8   : [NCODES][DIM] u8  = 16777216   (codebook scaled by 4096)
// norms   : [NCODES] float  (unscaled ||e||^2, fp32-exact)
// rownorm : [NROWS] float   (||x||^2, fp32-exact)
// argmin  : [NROWS] u64     (sortable_f32(d) << 32 | code_idx)
// counts  : [NCODES] u32
#define OFF_A      0UL
#define OFF_B      33554432UL
#define OFF_NORMS  50331648UL
#define OFF_RN     50348032UL
#define OFF_AMIN   50380800UL
#define OFF_COUNTS 50446336UL

__device__ __forceinline__ void stage16(const void* g, void* l) {
  __builtin_amdgcn_global_load_lds(
      (const __attribute__((address_space(1))) u32*)g,
      (__attribute__((address_space(3))) u32*)l, 16, 0, 0);
}

// float -> OCP e4m3fn, RNE, saturate to 448. Data is finite (no NaN path).
__device__ __forceinline__ u32 f2fp8(float f) {
  u32 u = __float_as_uint(f);
  u32 sign = (u >> 24) & 0x80u;
  u32 mag = u & 0x7FFFFFFFu;
  if (mag > 0x43E00000u) mag = 0x43E00000u;          // sat to 448
  u32 b;
  if (mag < 0x3C800000u) {                            // < 2^-6 : subnormal
    b = (u32)__float2int_rn(__uint_as_float(mag) * 512.0f);
  } else {
    u32 m = mag + 0x7FFFFu + ((mag >> 20) & 1u);      // RNE at 20-bit boundary
    u32 e = (m >> 23) - 127u;
    b = (((e + 7u) << 3) | ((m >> 20) & 7u)) & 0x7Fu;
  }
  return sign | b;
}

__device__ __forceinline__ u32 pack4(float4 v) {
  return f2fp8(v.x) | (f2fp8(v.y) << 8) | (f2fp8(v.z) << 16) | (f2fp8(v.w) << 24);
}

__device__ __forceinline__ float waveRed(float s) {
#pragma unroll
  for (int off = 32; off > 0; off >>= 1) s += __shfl_down(s, off);
  return s;
}

__device__ __forceinline__ i32x8 comb(i32x4 lo, i32x4 hi) {
  i32x8 r;
  r[0] = lo[0]; r[1] = lo[1]; r[2] = lo[2]; r[3] = lo[3];
  r[4] = hi[0]; r[5] = hi[1]; r[6] = hi[2]; r[7] = hi[3];
  return r;
}

// ---------------- init ----------------
__global__ void k_init(u64* __restrict__ amin, u32* __restrict__ counts) {
  int t = blockIdx.x * 256 + threadIdx.x;
  if (t < NROWS) amin[t] = ~0ULL;
  if (t < NCODES) counts[t] = 0u;
}

// ---------------- inputs: fp32 -> fp8 + ||x||^2 per row ----------------
__global__ void k_cvtA(const float4* __restrict__ in, u32* __restrict__ outA,
                       float* __restrict__ rn) {
  int r = blockIdx.x;
  const float4* src = in + (size_t)r * (DIM / 4);
  u32* dst = outA + (size_t)r * (DIM / 4);
  float s = 0.0f;
#pragma unroll
  for (int q = 0; q < 4; ++q) {
    int j = q * 256 + threadIdx.x;
    float4 v = src[j];
    s += v.x * v.x + v.y * v.y + v.z * v.z + v.w * v.w;
    dst[j] = pack4(v);
  }
  s = waveRed(s);
  __shared__ float red[4];
  int wid = threadIdx.x >> 6, lane = threadIdx.x & 63;
  if (lane == 0) red[wid] = s;
  __syncthreads();
  if (threadIdx.x == 0) rn[r] = red[0] + red[1] + red[2] + red[3];
}

// ---------------- codebook: fp32 -> fp8*4096 + ||e||^2 ----------------
__global__ void k_cvtB(const float* __restrict__ cb, u32* __restrict__ Bb,
                       float* __restrict__ norms) {
  int row = blockIdx.x;
  const float4* src = (const float4*)(cb + (size_t)row * DIM);
  u32* dst = Bb + (size_t)row * (DIM / 4);
  float s = 0.0f;
#pragma unroll
  for (int q = 0; q < 4; ++q) {
    int j = q * 256 + threadIdx.x;
    float4 v = src[j];
    s += v.x * v.x + v.y * v.y + v.z * v.z + v.w * v.w;
    float4 sv;
    sv.x = v.x * 4096.0f; sv.y = v.y * 4096.0f;
    sv.z = v.z * 4096.0f; sv.w = v.w * 4096.0f;
    dst[j] = pack4(sv);
  }
  s = waveRed(s);
  __shared__ float red[4];
  int wid = threadIdx.x >> 6, lane = threadIdx.x & 63;
  if (lane == 0) red[wid] = s;
  __syncthreads();
  if (threadIdx.x == 0) norms[row] = red[0] + red[1] + red[2] + red[3];
}

// ---------------- MX-fp8 GEMM (x . e^T) + per-row argmin ----------------
// 128x128 tile, BK=128 fp8, 4 waves (2x2 of 64x64), 16x16x128 f8f6f4 MFMA,
// unit scales. LDS chunk-swizzled (both-sides): global source chunk is
// XOR'd with row&7 at stage time (linear LDS dest, rule #21), fragment
// reads XOR the chunk position -> conflict-free (8 lanes/chunk over all
// 8 chunks per ds_read_b128 issue).
__launch_bounds__(256)
__global__ void k_gemm_argmin(const u8* __restrict__ A,
                              const u8* __restrict__ B,
                              const float* __restrict__ norms,
                              u64* __restrict__ amin) {
  __shared__ u8 As[128 * BK];   // 16 KiB
  __shared__ u8 Bs[128 * BK];   // 16 KiB

  const int bm = blockIdx.x;
  const int bn = blockIdx.y;
  const int tid = threadIdx.x;
  const int w = tid >> 6;
  const int lane = tid & 63;
  const int wr = w >> 1, wc = w & 1;
  const int g = lane >> 4, c = lane & 15;

  const size_t rowA0 = (size_t)bm * 128;
  const size_t rowB0 = (size_t)bn * 128;

  // stage-side swizzle: thread fills LDS chunk (tid&7) of row j*32+(tid>>3);
  // fetch global chunk (tid&7) ^ (row&7); row&7 == (tid>>3)&7 for all j.
  const int colb = (((tid & 7) ^ ((tid >> 3) & 7)) << 4);
  const int srow = tid >> 3;            // row within tile for j=0

  // read-side swizzle: fragment row&7 == c&7 for every m/n.
  const int colo = (((2 * g) ^ (c & 7)) << 4);
  const int cohi = (((2 * g + 1) ^ (c & 7)) << 4);

  f32x4 acc[4][4] = {};

  for (int kt = 0; kt < KSTEPS; ++kt) {
    __syncthreads();
#pragma unroll
    for (int j = 0; j < 4; ++j) {
      int o = j * 4096 + tid * 16;      // linear LDS dest
      int row = j * 32 + srow;
      stage16(A + (rowA0 + row) * DIM + (size_t)kt * BK + colb, (char*)As + o);
      stage16(B + (rowB0 + row) * DIM + (size_t)kt * BK + colb, (char*)Bs + o);
    }
    __syncthreads();

    i32x8 af[4], bv[4];
#pragma unroll
    for (int m = 0; m < 4; ++m) {
      int rowm = (wr * 64 + m * 16 + c) * BK;
      af[m] = comb(*(const i32x4*)&As[rowm + colo],
                   *(const i32x4*)&As[rowm + cohi]);
    }
#pragma unroll
    for (int n = 0; n < 4; ++n) {
      int rown = (wc * 64 + n * 16 + c) * BK;
      bv[n] = comb(*(const i32x4*)&Bs[rown + colo],
                   *(const i32x4*)&Bs[rown + cohi]);
    }
#pragma unroll
    for (int m = 0; m < 4; ++m)
#pragma unroll
      for (int n = 0; n < 4; ++n)
        acc[m][n] = __builtin_amdgcn_mfma_scale_f32_16x16x128_f8f6f4(
            af[m], bv[n], acc[m][n], 0, 0, 0, 0x7F7F7F7F, 0, 0x7F7F7F7F);
  }

  // epilogue: d = ||e||^2 - (2/4096)*acc ; argmin over this block's 128 cols
  const int rowBase = bm * 128 + wr * 64;
  const int colBase = bn * 128 + wc * 64;
  float nr[4];
#pragma unroll
  for (int n = 0; n < 4; ++n) nr[n] = norms[colBase + n * 16 + c];

#pragma unroll
  for (int m = 0; m < 4; ++m) {
#pragma unroll
    for (int j = 0; j < 4; ++j) {
      u64 key = ~0ULL;
#pragma unroll
      for (int n = 0; n < 4; ++n) {
        float d = nr[n] - acc[m][n][j] * 4.8828125e-4f;   // 2/4096
        u32 u = __float_as_uint(d);
        u = (u & 0x80000000u) ? ~u : (u | 0x80000000u);
        u64 k2 = ((u64)u << 32) | (u32)(colBase + n * 16 + c);
        if (k2 < key) key = k2;
      }
#pragma unroll
      for (int off = 1; off < 16; off <<= 1) {
        u64 o = __shfl_xor(key, off);
        if (o < key) key = o;
      }
      if (c == 0) atomicMin(&amin[rowBase + m * 16 + g * 4 + j], key);
    }
  }
}

// ---------------- gather -> output + counts ----------------
__global__ void k_out(const float4* __restrict__ cb, const u64* __restrict__ amin,
                      float4* __restrict__ out, u32* __restrict__ counts) {
  int r = blockIdx.x;
  u32 idx = (u32)(amin[r] & 0xFFFFFFFFu);
  if (threadIdx.x == 0) atomicAdd(&counts[idx], 1u);
  const float4* crow = cb + (size_t)idx * (DIM / 4);
  float4* orow = out + (size_t)r * (DIM / 4);
#pragma unroll
  for (int q = 0; q < 4; ++q) {
    int j = q * 256 + threadIdx.x;
    orow[j] = crow[j];
  }
}

// ---------------- finalize: loss (from distances) + perplexity ----------------
__global__ void k_final(const u32* __restrict__ counts, const u64* __restrict__ amin,
                        const float* __restrict__ rn, float* __restrict__ out) {
  float acc = 0.0f;
  for (int r = threadIdx.x; r < NROWS; r += 256) {
    u32 u = (u32)(amin[r] >> 32);
    u32 b = (u & 0x80000000u) ? (u & 0x7FFFFFFFu) : ~u;  // undo sortable map
    acc += __uint_as_float(b) + rn[r];   // d_min + ||x||^2 = ||x - e||^2
  }
  float ent = 0.0f;
  for (int i = threadIdx.x; i < NCODES; i += 256) {
    float p = (float)counts[i] * (1.0f / (float)NROWS);
    ent -= p * logf(p + 1e-10f);
  }
  acc = waveRed(acc);
  ent = waveRed(ent);
  __shared__ float ra[4], re[4];
  int wid = threadIdx.x >> 6, lane = threadIdx.x & 63;
  if (lane == 0) { ra[wid] = acc; re[wid] = ent; }
  __syncthreads();
  if (threadIdx.x == 0) {
    float sse = ra[0] + ra[1] + ra[2] + ra[3];
    float e = re[0] + re[1] + re[2] + re[3];
    out[(size_t)NROWS * DIM] = 1.25f * sse * (1.0f / (float)((size_t)NROWS * DIM));
    out[(size_t)NROWS * DIM + 1] = expf(e);
  }
}

extern "C" void kernel_launch(void* const* d_in, const int* in_sizes, int n_in,
                              void* d_out, int out_size, void* d_ws, size_t ws_size,
                              hipStream_t stream) {
  const float* d_inputs = (const float*)d_in[0];
  const float* d_cb = (const float*)d_in[1];
  float* out = (float*)d_out;
  char* ws = (char*)d_ws;

  u8* A = (u8*)(ws + OFF_A);
  u8* B = (u8*)(ws + OFF_B);
  float* norms = (float*)(ws + OFF_NORMS);
  float* rn = (float*)(ws + OFF_RN);
  u64* amin = (u64*)(ws + OFF_AMIN);
  u32* counts = (u32*)(ws + OFF_COUNTS);

  k_init<<<32, 256, 0, stream>>>(amin, counts);
  k_cvtA<<<NROWS, 256, 0, stream>>>((const float4*)d_inputs, (u32*)A, rn);
  k_cvtB<<<NCODES, 256, 0, stream>>>(d_cb, (u32*)B, norms);
  dim3 grid(NROWS / 128, NCODES / 128);
  k_gemm_argmin<<<grid, 256, 0, stream>>>(A, B, norms, amin);
  k_out<<<NROWS, 256, 0, stream>>>((const float4*)d_cb, amin, (float4*)out, counts);
  k_final<<<1, 256, 0, stream>>>(counts, amin, rn, out);
}

// Round 4
// 265.924 us; speedup vs baseline: 1.8669x; 1.0114x over previous
//
#include <hip/hip_runtime.h>
#include <hip/hip_bf16.h>
#include <stdint.h>

typedef unsigned int u32;
typedef unsigned char u8;
typedef unsigned long long u64;
typedef __attribute__((ext_vector_type(8))) int i32x8;
typedef __attribute__((ext_vector_type(4))) int i32x4;
typedef __attribute__((ext_vector_type(4))) float f32x4;

#define NROWS 8192    // 16*512
#define NCODES 4096
#define DIM 4096
#define BK 128
#define KSTEPS (DIM / BK)   // 32

// ---------------- workspace layout (bytes) ----------------
#define OFF_A      0UL
#define OFF_B      33554432UL
#define OFF_NORMS  50331648UL
#define OFF_RN     50348032UL
#define OFF_AMIN   50380800UL
#define OFF_COUNTS 50446336UL

__device__ __forceinline__ void stage16(const void* g, void* l) {
  __builtin_amdgcn_global_load_lds(
      (const __attribute__((address_space(1))) u32*)g,
      (__attribute__((address_space(3))) u32*)l, 16, 0, 0);
}

// float -> OCP e4m3fn, RNE, saturate to 448. Data is finite (no NaN path).
__device__ __forceinline__ u32 f2fp8(float f) {
  u32 u = __float_as_uint(f);
  u32 sign = (u >> 24) & 0x80u;
  u32 mag = u & 0x7FFFFFFFu;
  if (mag > 0x43E00000u) mag = 0x43E00000u;          // sat to 448
  u32 b;
  if (mag < 0x3C800000u) {                            // < 2^-6 : subnormal
    b = (u32)__float2int_rn(__uint_as_float(mag) * 512.0f);
  } else {
    u32 m = mag + 0x7FFFFu + ((mag >> 20) & 1u);      // RNE at 20-bit boundary
    u32 e = (m >> 23) - 127u;
    b = (((e + 7u) << 3) | ((m >> 20) & 7u)) & 0x7Fu;
  }
  return sign | b;
}

__device__ __forceinline__ u32 pack4(float4 v) {
  return f2fp8(v.x) | (f2fp8(v.y) << 8) | (f2fp8(v.z) << 16) | (f2fp8(v.w) << 24);
}

__device__ __forceinline__ float waveRed(float s) {
#pragma unroll
  for (int off = 32; off > 0; off >>= 1) s += __shfl_down(s, off);
  return s;
}

__device__ __forceinline__ i32x8 comb(i32x4 lo, i32x4 hi) {
  i32x8 r;
  r[0] = lo[0]; r[1] = lo[1]; r[2] = lo[2]; r[3] = lo[3];
  r[4] = hi[0]; r[5] = hi[1]; r[6] = hi[2]; r[7] = hi[3];
  return r;
}

// ---------------- init ----------------
__global__ void k_init(u64* __restrict__ amin, u32* __restrict__ counts) {
  int t = blockIdx.x * 256 + threadIdx.x;
  if (t < NROWS) amin[t] = ~0ULL;
  if (t < NCODES) counts[t] = 0u;
}

// ---------------- inputs: fp32 -> fp8 + ||x||^2 per row ----------------
__global__ void k_cvtA(const float4* __restrict__ in, u32* __restrict__ outA,
                       float* __restrict__ rn) {
  int r = blockIdx.x;
  const float4* src = in + (size_t)r * (DIM / 4);
  u32* dst = outA + (size_t)r * (DIM / 4);
  float s = 0.0f;
#pragma unroll
  for (int q = 0; q < 4; ++q) {
    int j = q * 256 + threadIdx.x;
    float4 v = src[j];
    s += v.x * v.x + v.y * v.y + v.z * v.z + v.w * v.w;
    dst[j] = pack4(v);
  }
  s = waveRed(s);
  __shared__ float red[4];
  int wid = threadIdx.x >> 6, lane = threadIdx.x & 63;
  if (lane == 0) red[wid] = s;
  __syncthreads();
  if (threadIdx.x == 0) rn[r] = red[0] + red[1] + red[2] + red[3];
}

// ---------------- codebook: fp32 -> fp8*4096 + ||e||^2 ----------------
__global__ void k_cvtB(const float* __restrict__ cb, u32* __restrict__ Bb,
                       float* __restrict__ norms) {
  int row = blockIdx.x;
  const float4* src = (const float4*)(cb + (size_t)row * DIM);
  u32* dst = Bb + (size_t)row * (DIM / 4);
  float s = 0.0f;
#pragma unroll
  for (int q = 0; q < 4; ++q) {
    int j = q * 256 + threadIdx.x;
    float4 v = src[j];
    s += v.x * v.x + v.y * v.y + v.z * v.z + v.w * v.w;
    float4 sv;
    sv.x = v.x * 4096.0f; sv.y = v.y * 4096.0f;
    sv.z = v.z * 4096.0f; sv.w = v.w * 4096.0f;
    dst[j] = pack4(sv);
  }
  s = waveRed(s);
  __shared__ float red[4];
  int wid = threadIdx.x >> 6, lane = threadIdx.x & 63;
  if (lane == 0) red[wid] = s;
  __syncthreads();
  if (threadIdx.x == 0) norms[row] = red[0] + red[1] + red[2] + red[3];
}

// ---------------- MX-fp8 GEMM (x . e^T) + per-row argmin ----------------
// 128x128 tile, BK=128 fp8, 4 waves (2x2 of 64x64), 16x16x128 f8f6f4 MFMA,
// unit scales. Chunk swizzle as R3 (pre-swizzled global source, linear LDS
// dest, swizzled reads). NEW: T3 minimum-2-phase prefetch — double-buffered
// LDS, next tile's global_load_lds issued BEFORE current compute, raw
// s_barrier + counted waits (one barrier per K-step, no compiler drain).
__launch_bounds__(256)
__global__ void k_gemm_argmin(const u8* __restrict__ A,
                              const u8* __restrict__ B,
                              const float* __restrict__ norms,
                              u64* __restrict__ amin) {
  __shared__ u8 As[2][128 * BK];   // 2 x 16 KiB
  __shared__ u8 Bs[2][128 * BK];   // 2 x 16 KiB

  const int bm = blockIdx.x;
  const int bn = blockIdx.y;
  const int tid = threadIdx.x;
  const int w = tid >> 6;
  const int lane = tid & 63;
  const int wr = w >> 1, wc = w & 1;
  const int g = lane >> 4, c = lane & 15;

  const size_t rowA0 = (size_t)bm * 128;
  const size_t rowB0 = (size_t)bn * 128;

  // stage-side swizzle: thread fills LDS chunk (tid&7) of row j*32+(tid>>3);
  // fetch global chunk (tid&7) ^ (row&7).
  const int colb = (((tid & 7) ^ ((tid >> 3) & 7)) << 4);
  const int srow = tid >> 3;
  const u8* gA = A + rowA0 * DIM + colb;
  const u8* gB = B + rowB0 * DIM + colb;

  // read-side swizzle: fragment row&7 == c&7.
  const int colo = (((2 * g) ^ (c & 7)) << 4);
  const int cohi = (((2 * g + 1) ^ (c & 7)) << 4);

  f32x4 acc[4][4] = {};

  // ---- prologue: stage tile 0 into buffer 0, drain, sync ----
#pragma unroll
  for (int j = 0; j < 4; ++j) {
    int o = j * 4096 + tid * 16;
    int row = j * 32 + srow;
    stage16(gA + (size_t)row * DIM, (char*)As[0] + o);
    stage16(gB + (size_t)row * DIM, (char*)Bs[0] + o);
  }
  asm volatile("s_waitcnt vmcnt(0)" ::: "memory");
  __builtin_amdgcn_s_barrier();
  __builtin_amdgcn_sched_barrier(0);

#pragma unroll 2
  for (int kt = 0; kt < KSTEPS; ++kt) {
    const int cur = kt & 1;
    // issue next tile's stages first (overlap with compute below)
    if (kt + 1 < KSTEPS) {
#pragma unroll
      for (int j = 0; j < 4; ++j) {
        int o = j * 4096 + tid * 16;
        int row = j * 32 + srow;
        stage16(gA + (size_t)row * DIM + (size_t)(kt + 1) * BK,
                (char*)As[cur ^ 1] + o);
        stage16(gB + (size_t)row * DIM + (size_t)(kt + 1) * BK,
                (char*)Bs[cur ^ 1] + o);
      }
    }
    __builtin_amdgcn_sched_barrier(0);

    // compute current buffer (compiler manages lgkm waits for ds_read->MFMA)
    i32x8 af[4], bv[4];
#pragma unroll
    for (int m = 0; m < 4; ++m) {
      int rowm = (wr * 64 + m * 16 + c) * BK;
      af[m] = comb(*(const i32x4*)&As[cur][rowm + colo],
                   *(const i32x4*)&As[cur][rowm + cohi]);
    }
#pragma unroll
    for (int n = 0; n < 4; ++n) {
      int rown = (wc * 64 + n * 16 + c) * BK;
      bv[n] = comb(*(const i32x4*)&Bs[cur][rown + colo],
                   *(const i32x4*)&Bs[cur][rown + cohi]);
    }
#pragma unroll
    for (int m = 0; m < 4; ++m)
#pragma unroll
      for (int n = 0; n < 4; ++n)
        acc[m][n] = __builtin_amdgcn_mfma_scale_f32_16x16x128_f8f6f4(
            af[m], bv[n], acc[m][n], 0, 0, 0, 0x7F7F7F7F, 0, 0x7F7F7F7F);

    // next tile's stage-writes landed; all waves' reads of cur done (MFMA
    // deps) -> after this barrier it is safe to overwrite buf[cur].
    asm volatile("s_waitcnt vmcnt(0)" ::: "memory");
    __builtin_amdgcn_s_barrier();
    __builtin_amdgcn_sched_barrier(0);
  }

  // epilogue: d = ||e||^2 - (2/4096)*acc ; argmin over this block's 128 cols
  const int rowBase = bm * 128 + wr * 64;
  const int colBase = bn * 128 + wc * 64;
  float nr[4];
#pragma unroll
  for (int n = 0; n < 4; ++n) nr[n] = norms[colBase + n * 16 + c];

#pragma unroll
  for (int m = 0; m < 4; ++m) {
#pragma unroll
    for (int j = 0; j < 4; ++j) {
      u64 key = ~0ULL;
#pragma unroll
      for (int n = 0; n < 4; ++n) {
        float d = nr[n] - acc[m][n][j] * 4.8828125e-4f;   // 2/4096
        u32 u = __float_as_uint(d);
        u = (u & 0x80000000u) ? ~u : (u | 0x80000000u);
        u64 k2 = ((u64)u << 32) | (u32)(colBase + n * 16 + c);
        if (k2 < key) key = k2;
      }
#pragma unroll
      for (int off = 1; off < 16; off <<= 1) {
        u64 o = __shfl_xor(key, off);
        if (o < key) key = o;
      }
      if (c == 0) atomicMin(&amin[rowBase + m * 16 + g * 4 + j], key);
    }
  }
}

// ---------------- gather -> output + counts ----------------
__global__ void k_out(const float4* __restrict__ cb, const u64* __restrict__ amin,
                      float4* __restrict__ out, u32* __restrict__ counts) {
  int r = blockIdx.x;
  u32 idx = (u32)(amin[r] & 0xFFFFFFFFu);
  if (threadIdx.x == 0) atomicAdd(&counts[idx], 1u);
  const float4* crow = cb + (size_t)idx * (DIM / 4);
  float4* orow = out + (size_t)r * (DIM / 4);
#pragma unroll
  for (int q = 0; q < 4; ++q) {
    int j = q * 256 + threadIdx.x;
    orow[j] = crow[j];
  }
}

// ---------------- finalize: loss (from distances) + perplexity ----------------
__global__ void k_final(const u32* __restrict__ counts, const u64* __restrict__ amin,
                        const float* __restrict__ rn, float* __restrict__ out) {
  float acc = 0.0f;
  for (int r = threadIdx.x; r < NROWS; r += 256) {
    u32 u = (u32)(amin[r] >> 32);
    u32 b = (u & 0x80000000u) ? (u & 0x7FFFFFFFu) : ~u;  // undo sortable map
    acc += __uint_as_float(b) + rn[r];   // d_min + ||x||^2 = ||x - e||^2
  }
  float ent = 0.0f;
  for (int i = threadIdx.x; i < NCODES; i += 256) {
    float p = (float)counts[i] * (1.0f / (float)NROWS);
    ent -= p * logf(p + 1e-10f);
  }
  acc = waveRed(acc);
  ent = waveRed(ent);
  __shared__ float ra[4], re[4];
  int wid = threadIdx.x >> 6, lane = threadIdx.x & 63;
  if (lane == 0) { ra[wid] = acc; re[wid] = ent; }
  __syncthreads();
  if (threadIdx.x == 0) {
    float sse = ra[0] + ra[1] + ra[2] + ra[3];
    float e = re[0] + re[1] + re[2] + re[3];
    out[(size_t)NROWS * DIM] = 1.25f * sse * (1.0f / (float)((size_t)NROWS * DIM));
    out[(size_t)NROWS * DIM + 1] = expf(e);
  }
}

extern "C" void kernel_launch(void* const* d_in, const int* in_sizes, int n_in,
                              void* d_out, int out_size, void* d_ws, size_t ws_size,
                              hipStream_t stream) {
  const float* d_inputs = (const float*)d_in[0];
  const float* d_cb = (const float*)d_in[1];
  float* out = (float*)d_out;
  char* ws = (char*)d_ws;

  u8* A = (u8*)(ws + OFF_A);
  u8* B = (u8*)(ws + OFF_B);
  float* norms = (float*)(ws + OFF_NORMS);
  float* rn = (float*)(ws + OFF_RN);
  u64* amin = (u64*)(ws + OFF_AMIN);
  u32* counts = (u32*)(ws + OFF_COUNTS);

  k_init<<<32, 256, 0, stream>>>(amin, counts);
  k_cvtA<<<NROWS, 256, 0, stream>>>((const float4*)d_inputs, (u32*)A, rn);
  k_cvtB<<<NCODES, 256, 0, stream>>>(d_cb, (u32*)B, norms);
  dim3 grid(NROWS / 128, NCODES / 128);
  k_gemm_argmin<<<grid, 256, 0, stream>>>(A, B, norms, amin);
  k_out<<<NROWS, 256, 0, stream>>>((const float4*)d_cb, amin, (float4*)out, counts);
  k_final<<<1, 256, 0, stream>>>(counts, amin, rn, out);
}

// Round 5
// 248.738 us; speedup vs baseline: 1.9959x; 1.0691x over previous
//
#include <hip/hip_runtime.h>
#include <hip/hip_bf16.h>
#include <stdint.h>

typedef unsigned int u32;
typedef unsigned char u8;
typedef unsigned long long u64;
typedef __attribute__((ext_vector_type(8))) int i32x8;
typedef __attribute__((ext_vector_type(4))) int i32x4;
typedef __attribute__((ext_vector_type(4))) float f32x4;

#define NROWS 8192    // 16*512
#define NCODES 4096
#define DIM 4096
#define BK 128
#define KSTEPS (DIM / BK)   // 32
#define BM 256
#define BN 256

// ---------------- workspace layout (bytes) ----------------
#define OFF_A      0UL
#define OFF_B      33554432UL
#define OFF_NORMS  50331648UL
#define OFF_RN     50348032UL
#define OFF_AMIN   50380800UL
#define OFF_COUNTS 50446336UL

__device__ __forceinline__ void stage16(const void* g, void* l) {
  __builtin_amdgcn_global_load_lds(
      (const __attribute__((address_space(1))) u32*)g,
      (__attribute__((address_space(3))) u32*)l, 16, 0, 0);
}

// float -> OCP e4m3fn, RNE, saturate to 448. Data is finite (no NaN path).
__device__ __forceinline__ u32 f2fp8(float f) {
  u32 u = __float_as_uint(f);
  u32 sign = (u >> 24) & 0x80u;
  u32 mag = u & 0x7FFFFFFFu;
  if (mag > 0x43E00000u) mag = 0x43E00000u;          // sat to 448
  u32 b;
  if (mag < 0x3C800000u) {                            // < 2^-6 : subnormal
    b = (u32)__float2int_rn(__uint_as_float(mag) * 512.0f);
  } else {
    u32 m = mag + 0x7FFFFu + ((mag >> 20) & 1u);      // RNE at 20-bit boundary
    u32 e = (m >> 23) - 127u;
    b = (((e + 7u) << 3) | ((m >> 20) & 7u)) & 0x7Fu;
  }
  return sign | b;
}

__device__ __forceinline__ u32 pack4(float4 v) {
  return f2fp8(v.x) | (f2fp8(v.y) << 8) | (f2fp8(v.z) << 16) | (f2fp8(v.w) << 24);
}

__device__ __forceinline__ float waveRed(float s) {
#pragma unroll
  for (int off = 32; off > 0; off >>= 1) s += __shfl_down(s, off);
  return s;
}

__device__ __forceinline__ i32x8 comb(i32x4 lo, i32x4 hi) {
  i32x8 r;
  r[0] = lo[0]; r[1] = lo[1]; r[2] = lo[2]; r[3] = lo[3];
  r[4] = hi[0]; r[5] = hi[1]; r[6] = hi[2]; r[7] = hi[3];
  return r;
}

// ---------------- init ----------------
__global__ void k_init(u64* __restrict__ amin, u32* __restrict__ counts) {
  int t = blockIdx.x * 256 + threadIdx.x;
  if (t < NROWS) amin[t] = ~0ULL;
  if (t < NCODES) counts[t] = 0u;
}

// ---------------- inputs: fp32 -> fp8 + ||x||^2 per row ----------------
__global__ void k_cvtA(const float4* __restrict__ in, u32* __restrict__ outA,
                       float* __restrict__ rn) {
  int r = blockIdx.x;
  const float4* src = in + (size_t)r * (DIM / 4);
  u32* dst = outA + (size_t)r * (DIM / 4);
  float s = 0.0f;
#pragma unroll
  for (int q = 0; q < 4; ++q) {
    int j = q * 256 + threadIdx.x;
    float4 v = src[j];
    s += v.x * v.x + v.y * v.y + v.z * v.z + v.w * v.w;
    dst[j] = pack4(v);
  }
  s = waveRed(s);
  __shared__ float red[4];
  int wid = threadIdx.x >> 6, lane = threadIdx.x & 63;
  if (lane == 0) red[wid] = s;
  __syncthreads();
  if (threadIdx.x == 0) rn[r] = red[0] + red[1] + red[2] + red[3];
}

// ---------------- codebook: fp32 -> fp8*4096 + ||e||^2 ----------------
__global__ void k_cvtB(const float* __restrict__ cb, u32* __restrict__ Bb,
                       float* __restrict__ norms) {
  int row = blockIdx.x;
  const float4* src = (const float4*)(cb + (size_t)row * DIM);
  u32* dst = Bb + (size_t)row * (DIM / 4);
  float s = 0.0f;
#pragma unroll
  for (int q = 0; q < 4; ++q) {
    int j = q * 256 + threadIdx.x;
    float4 v = src[j];
    s += v.x * v.x + v.y * v.y + v.z * v.z + v.w * v.w;
    float4 sv;
    sv.x = v.x * 4096.0f; sv.y = v.y * 4096.0f;
    sv.z = v.z * 4096.0f; sv.w = v.w * 4096.0f;
    dst[j] = pack4(sv);
  }
  s = waveRed(s);
  __shared__ float red[4];
  int wid = threadIdx.x >> 6, lane = threadIdx.x & 63;
  if (lane == 0) red[wid] = s;
  __syncthreads();
  if (threadIdx.x == 0) norms[row] = red[0] + red[1] + red[2] + red[3];
}

// ---------------- MX-fp8 GEMM (x . e^T) + per-row argmin ----------------
// 256x256 tile, BK=128 fp8, 8 waves (2 M x 4 N), wave tile 128x64,
// 16x16x128 f8f6f4 MFMA with unit scales. Chunk swizzle (pre-swizzled
// global source, linear LDS dest, swizzled conflict-free reads) +
// double-buffered 2-phase prefetch with raw s_barrier + vmcnt(0).
// Geometry rationale: 2x4 waves cut LDS read amplification to 4xA+2xB
// = 2048 cyc/K-step < MFMA 2212 cyc/K-step -> MFMA-bound.
__launch_bounds__(512, 2)
__global__ void k_gemm_argmin(const u8* __restrict__ A,
                              const u8* __restrict__ B,
                              const float* __restrict__ norms,
                              u64* __restrict__ amin) {
  __shared__ u8 As[2][BM * BK];   // 2 x 32 KiB
  __shared__ u8 Bs[2][BN * BK];   // 2 x 32 KiB

  const int bm = blockIdx.x;
  const int bn = blockIdx.y;
  const int tid = threadIdx.x;
  const int w = tid >> 6;
  const int lane = tid & 63;
  const int wr = w >> 2, wc = w & 3;   // 2 x 4 wave grid
  const int g = lane >> 4, c = lane & 15;

  const size_t rowA0 = (size_t)bm * BM;
  const size_t rowB0 = (size_t)bn * BN;

  // stage-side swizzle: thread fills LDS chunk (tid&7) of row j*64+(tid>>3);
  // fetches global chunk (tid&7) ^ (row&7); row&7 == (tid>>3)&7 for all j.
  const int colb = (((tid & 7) ^ ((tid >> 3) & 7)) << 4);
  const int srow = tid >> 3;
  const u8* gA = A + rowA0 * DIM + colb;
  const u8* gB = B + rowB0 * DIM + colb;

  // read-side swizzle: fragment row&7 == c&7 for every m/n.
  const int colo = (((2 * g) ^ (c & 7)) << 4);
  const int cohi = (((2 * g + 1) ^ (c & 7)) << 4);

  f32x4 acc[8][4] = {};

  // ---- prologue: stage tile 0 into buffer 0 ----
#pragma unroll
  for (int j = 0; j < 4; ++j) {
    int o = j * 8192 + tid * 16;
    int row = j * 64 + srow;
    stage16(gA + (size_t)row * DIM, (char*)As[0] + o);
    stage16(gB + (size_t)row * DIM, (char*)Bs[0] + o);
  }
  asm volatile("s_waitcnt vmcnt(0)" ::: "memory");
  __builtin_amdgcn_s_barrier();
  __builtin_amdgcn_sched_barrier(0);

#pragma unroll 2
  for (int kt = 0; kt < KSTEPS; ++kt) {
    const int cur = kt & 1;
    // issue next tile's stages first (their latency hides under compute)
    if (kt + 1 < KSTEPS) {
#pragma unroll
      for (int j = 0; j < 4; ++j) {
        int o = j * 8192 + tid * 16;
        int row = j * 64 + srow;
        stage16(gA + (size_t)row * DIM + (size_t)(kt + 1) * BK,
                (char*)As[cur ^ 1] + o);
        stage16(gB + (size_t)row * DIM + (size_t)(kt + 1) * BK,
                (char*)Bs[cur ^ 1] + o);
      }
    }
    __builtin_amdgcn_sched_barrier(0);

    // compute current buffer
    i32x8 bv[4];
#pragma unroll
    for (int n = 0; n < 4; ++n) {
      int rown = (wc * 64 + n * 16 + c) * BK;
      bv[n] = comb(*(const i32x4*)&Bs[cur][rown + colo],
                   *(const i32x4*)&Bs[cur][rown + cohi]);
    }
#pragma unroll
    for (int m = 0; m < 8; ++m) {
      int rowm = (wr * 128 + m * 16 + c) * BK;
      i32x8 af = comb(*(const i32x4*)&As[cur][rowm + colo],
                      *(const i32x4*)&As[cur][rowm + cohi]);
#pragma unroll
      for (int n = 0; n < 4; ++n)
        acc[m][n] = __builtin_amdgcn_mfma_scale_f32_16x16x128_f8f6f4(
            af, bv[n], acc[m][n], 0, 0, 0, 0x7F7F7F7F, 0, 0x7F7F7F7F);
    }

    // stage-writes for next tile landed; all waves' reads of cur complete.
    asm volatile("s_waitcnt vmcnt(0)" ::: "memory");
    __builtin_amdgcn_s_barrier();
    __builtin_amdgcn_sched_barrier(0);
  }

  // epilogue: d = ||e||^2 - (2/4096)*acc ; argmin over this block's 256 cols
  const int rowBase = bm * BM + wr * 128;
  const int colBase = bn * BN + wc * 64;
  float nr[4];
#pragma unroll
  for (int n = 0; n < 4; ++n) nr[n] = norms[colBase + n * 16 + c];

#pragma unroll
  for (int m = 0; m < 8; ++m) {
#pragma unroll
    for (int j = 0; j < 4; ++j) {
      u64 key = ~0ULL;
#pragma unroll
      for (int n = 0; n < 4; ++n) {
        float d = nr[n] - acc[m][n][j] * 4.8828125e-4f;   // 2/4096
        u32 u = __float_as_uint(d);
        u = (u & 0x80000000u) ? ~u : (u | 0x80000000u);
        u64 k2 = ((u64)u << 32) | (u32)(colBase + n * 16 + c);
        if (k2 < key) key = k2;
      }
#pragma unroll
      for (int off = 1; off < 16; off <<= 1) {
        u64 o = __shfl_xor(key, off);
        if (o < key) key = o;
      }
      if (c == 0) atomicMin(&amin[rowBase + m * 16 + g * 4 + j], key);
    }
  }
}

// ---------------- gather -> output + counts ----------------
__global__ void k_out(const float4* __restrict__ cb, const u64* __restrict__ amin,
                      float4* __restrict__ out, u32* __restrict__ counts) {
  int r = blockIdx.x;
  u32 idx = (u32)(amin[r] & 0xFFFFFFFFu);
  if (threadIdx.x == 0) atomicAdd(&counts[idx], 1u);
  const float4* crow = cb + (size_t)idx * (DIM / 4);
  float4* orow = out + (size_t)r * (DIM / 4);
#pragma unroll
  for (int q = 0; q < 4; ++q) {
    int j = q * 256 + threadIdx.x;
    orow[j] = crow[j];
  }
}

// ---------------- finalize: loss (from distances) + perplexity ----------------
__global__ void k_final(const u32* __restrict__ counts, const u64* __restrict__ amin,
                        const float* __restrict__ rn, float* __restrict__ out) {
  float acc = 0.0f;
  for (int r = threadIdx.x; r < NROWS; r += 256) {
    u32 u = (u32)(amin[r] >> 32);
    u32 b = (u & 0x80000000u) ? (u & 0x7FFFFFFFu) : ~u;  // undo sortable map
    acc += __uint_as_float(b) + rn[r];   // d_min + ||x||^2 = ||x - e||^2
  }
  float ent = 0.0f;
  for (int i = threadIdx.x; i < NCODES; i += 256) {
    float p = (float)counts[i] * (1.0f / (float)NROWS);
    ent -= p * logf(p + 1e-10f);
  }
  acc = waveRed(acc);
  ent = waveRed(ent);
  __shared__ float ra[4], re[4];
  int wid = threadIdx.x >> 6, lane = threadIdx.x & 63;
  if (lane == 0) { ra[wid] = acc; re[wid] = ent; }
  __syncthreads();
  if (threadIdx.x == 0) {
    float sse = ra[0] + ra[1] + ra[2] + ra[3];
    float e = re[0] + re[1] + re[2] + re[3];
    out[(size_t)NROWS * DIM] = 1.25f * sse * (1.0f / (float)((size_t)NROWS * DIM));
    out[(size_t)NROWS * DIM + 1] = expf(e);
  }
}

extern "C" void kernel_launch(void* const* d_in, const int* in_sizes, int n_in,
                              void* d_out, int out_size, void* d_ws, size_t ws_size,
                              hipStream_t stream) {
  const float* d_inputs = (const float*)d_in[0];
  const float* d_cb = (const float*)d_in[1];
  float* out = (float*)d_out;
  char* ws = (char*)d_ws;

  u8* A = (u8*)(ws + OFF_A);
  u8* B = (u8*)(ws + OFF_B);
  float* norms = (float*)(ws + OFF_NORMS);
  float* rn = (float*)(ws + OFF_RN);
  u64* amin = (u64*)(ws + OFF_AMIN);
  u32* counts = (u32*)(ws + OFF_COUNTS);

  k_init<<<32, 256, 0, stream>>>(amin, counts);
  k_cvtA<<<NROWS, 256, 0, stream>>>((const float4*)d_inputs, (u32*)A, rn);
  k_cvtB<<<NCODES, 256, 0, stream>>>(d_cb, (u32*)B, norms);
  dim3 grid(NROWS / BM, NCODES / BN);
  k_gemm_argmin<<<grid, 512, 0, stream>>>(A, B, norms, amin);
  k_out<<<NROWS, 256, 0, stream>>>((const float4*)d_cb, amin, (float4*)out, counts);
  k_final<<<1, 256, 0, stream>>>(counts, amin, rn, out);
}